// Round 10
// baseline (731.892 us; speedup 1.0000x reference)
//
#include <hip/hip_runtime.h>
#include <stdint.h>

#define NN 131072
#define NE 4194304
#define BKT 256      // buckets (512 nodes each)
#define BKT_SH 9
#define BCAP 20480   // bucket capacity; mean 16384, sigma ~128

typedef __bf16 bf16x8 __attribute__((ext_vector_type(8)));
typedef float  floatx4 __attribute__((ext_vector_type(4)));
typedef unsigned short u16x8 __attribute__((ext_vector_type(8)));

__device__ __forceinline__ float bf2f(unsigned short u) {
  union { unsigned int i; float f; } v; v.i = ((unsigned int)u) << 16; return v.f;
}
__device__ __forceinline__ unsigned short f2bf(float f) {
  union { float f; unsigned int i; } v; v.f = f;
  unsigned int r = v.i + 0x7fffu + ((v.i >> 16) & 1u);  // RNE
  return (unsigned short)(r >> 16);
}

// ---------------- CSR build: LDS-histogram bucketing ----------------

__global__ __launch_bounds__(256) void k_bzero(int* __restrict__ bktCnt) {
  bktCnt[threadIdx.x] = 0;
}

// pass A: bin edges into 256 dst-buckets; packed edge = (src<<9)|(dst&511)
__global__ __launch_bounds__(1024) void k_bucket(const int* __restrict__ src,
                                                 const int* __restrict__ dst,
                                                 int* __restrict__ bktCnt,
                                                 unsigned int* __restrict__ bktBuf) {
  __shared__ int hist[BKT];
  __shared__ int base[BKT];
  const int t = threadIdx.x;
  if (t < BKT) hist[t] = 0;
  __syncthreads();
  const int e0 = (blockIdx.x * 1024 + t);
  const int4 s = ((const int4*)src)[e0];
  const int4 d = ((const int4*)dst)[e0];
  const int b0 = ((unsigned)d.x) >> BKT_SH, b1 = ((unsigned)d.y) >> BKT_SH;
  const int b2 = ((unsigned)d.z) >> BKT_SH, b3 = ((unsigned)d.w) >> BKT_SH;
  const int r0 = atomicAdd(&hist[b0], 1);
  const int r1 = atomicAdd(&hist[b1], 1);
  const int r2 = atomicAdd(&hist[b2], 1);
  const int r3 = atomicAdd(&hist[b3], 1);
  __syncthreads();
  if (t < BKT) base[t] = atomicAdd(&bktCnt[t], hist[t]);  // 256 global atomics/block
  __syncthreads();
  const unsigned p0 = (((unsigned)s.x) << BKT_SH) | (d.x & 511);
  const unsigned p1 = (((unsigned)s.y) << BKT_SH) | (d.y & 511);
  const unsigned p2 = (((unsigned)s.z) << BKT_SH) | (d.z & 511);
  const unsigned p3 = (((unsigned)s.w) << BKT_SH) | (d.w & 511);
  bktBuf[(size_t)b0 * BCAP + base[b0] + r0] = p0;
  bktBuf[(size_t)b1 * BCAP + base[b1] + r1] = p1;
  bktBuf[(size_t)b2 * BCAP + base[b2] + r2] = p2;
  bktBuf[(size_t)b3 * BCAP + base[b3] + r3] = p3;
}

// pass B: one block per bucket -> counts, row_ptr, dinv, csr fill
// 2-replica LDS histograms halve atomic contention.
__global__ __launch_bounds__(1024) void k_csr(const int* __restrict__ bktCnt,
                                              const unsigned int* __restrict__ bktBuf,
                                              int* __restrict__ row_ptr,
                                              float* __restrict__ dinv,
                                              int* __restrict__ csr) {
  __shared__ int bsum[BKT];
  __shared__ int histA[512];
  __shared__ int histB[512];
  __shared__ int sc[512];
  __shared__ int curA[512];
  __shared__ int curB[512];
  const int b = blockIdx.x;
  const int t = threadIdx.x;
  const int rep = t & 1;
  if (t < BKT) bsum[t] = bktCnt[t];
  if (t < 512) { histA[t] = 0; histB[t] = 0; }
  __syncthreads();
  // inclusive scan of bucket sizes (256)
  for (int off = 1; off < BKT; off <<= 1) {
    int v = 0;
    if (t < BKT && t >= off) v = bsum[t - off];
    __syncthreads();
    if (t < BKT) bsum[t] += v;
    __syncthreads();
  }
  const int sz = bktCnt[b];
  const int csrBase = bsum[b] - sz;  // exclusive prefix
  const unsigned int* eb = bktBuf + (size_t)b * BCAP;
  // local node histogram, replica by thread parity
  for (int i = t; i < sz; i += 1024)
    atomicAdd(rep ? &histB[eb[i] & 511] : &histA[eb[i] & 511], 1);
  __syncthreads();
  if (t < 512) sc[t] = histA[t] + histB[t];
  __syncthreads();
  for (int off = 1; off < 512; off <<= 1) {
    int v = 0;
    if (t < 512 && t >= off) v = sc[t - off];
    __syncthreads();
    if (t < 512) sc[t] += v;
    __syncthreads();
  }
  if (t < 512) {
    const int cnt = histA[t] + histB[t];
    const int ex = csrBase + sc[t] - cnt;  // exclusive
    row_ptr[b * 512 + t] = ex;
    curA[t] = ex;                 // replica-A fills [ex, ex+histA)
    curB[t] = ex + histA[t];      // replica-B fills [ex+histA, ex+cnt)
    dinv[b * 512 + t] = rsqrtf((float)(cnt + 1));
  }
  if (b == BKT - 1 && t == 0) row_ptr[NN] = NE;
  __syncthreads();
  // fill csr (bucket csr region = 64 KB -> L2-resident writes)
  for (int i = t; i < sz; i += 1024) {
    const unsigned e = eb[i];
    const int n = e & 511;
    const int pos = atomicAdd(rep ? &curB[n] : &curA[n], 1);
    csr[pos] = (int)(e >> BKT_SH);
  }
}

// ---------------- x fp32 -> bf16 ----------------
__global__ __launch_bounds__(256) void k_cvt(const float* __restrict__ X,
                                             unsigned short* __restrict__ Xb) {
  const int t = blockIdx.x * 256 + threadIdx.x;
  const float4 v = ((const float4*)X)[t];
  ushort4 o;
  o.x = f2bf(v.x); o.y = f2bf(v.y); o.z = f2bf(v.z); o.w = f2bf(v.w);
  ((ushort4*)Xb)[t] = o;
}

// ---------------- W1+W2 swizzle in one launch (fp32 -> bf16, MFMA B-frag order) ----------------
__global__ __launch_bounds__(256) void k_swizzle2(const float* __restrict__ W1,
                                                  unsigned short* __restrict__ Wsw1,
                                                  const float* __restrict__ W2,
                                                  unsigned short* __restrict__ Wsw2) {
  int b = blockIdx.x;
  const float* W; unsigned short* Wsw;
  if (b < 128) { W = W1; Wsw = Wsw1; } else { W = W2; Wsw = Wsw2; b -= 128; }
  const int t = b * 256 + threadIdx.x;  // t < K*256
  const int k = t >> 8, n = t & 255;
  const int s = ((k >> 5) * 16 + (n >> 4)) * 512 + ((k >> 3) & 3) * 128 + (n & 15) * 8 + (k & 7);
  Wsw[s] = f2bf(W[t]);
}

// ---------------- aggregation, feature-sliced pass ----------------
// One wave per node. 16 lanes per row gather 128 contiguous feats at foff.
__global__ __launch_bounds__(256) void agg_h(const unsigned short* __restrict__ X,
                                             const int* __restrict__ row_ptr,
                                             const int* __restrict__ csr,
                                             const float* __restrict__ dinv,
                                             unsigned short* __restrict__ Y,
                                             int F, int foff, int node_base) {
  const int lane = threadIdx.x & 63;
  const int node = node_base + ((blockIdx.x * blockDim.x + threadIdx.x) >> 6);
  const int sub = lane >> 4;   // 0..3
  const int fl = lane & 15;
  const int start = row_ptr[node];
  const int end = row_ptr[node + 1];
  const float di = dinv[node];
  float a[8] = {0.f, 0.f, 0.f, 0.f, 0.f, 0.f, 0.f, 0.f};
  const unsigned short* Xf = X + foff + fl * 8;

  for (int e = start; e < end; e += 64) {
    const int nload = min(end - e, 64);
    int s_l = node;
    float w_l = 0.0f;
    if (lane < nload) {
      s_l = __builtin_nontemporal_load(&csr[e + lane]);
      w_l = dinv[s_l];
    }
    for (int j = 0; j < nload; j += 16) {
      const int i0 = j + sub, i1 = j + 4 + sub, i2 = j + 8 + sub, i3 = j + 12 + sub;  // <= 63
      const int s0 = __shfl(s_l, i0); const float w0 = __shfl(w_l, i0);
      const int s1 = __shfl(s_l, i1); const float w1 = __shfl(w_l, i1);
      const int s2 = __shfl(s_l, i2); const float w2 = __shfl(w_l, i2);
      const int s3 = __shfl(s_l, i3); const float w3 = __shfl(w_l, i3);
      const u16x8 r0 = *(const u16x8*)(Xf + (size_t)s0 * F);
      const u16x8 r1 = *(const u16x8*)(Xf + (size_t)s1 * F);
      const u16x8 r2 = *(const u16x8*)(Xf + (size_t)s2 * F);
      const u16x8 r3 = *(const u16x8*)(Xf + (size_t)s3 * F);
#pragma unroll
      for (int i = 0; i < 8; ++i) a[i] = fmaf(w0, bf2f(r0[i]), a[i]);
#pragma unroll
      for (int i = 0; i < 8; ++i) a[i] = fmaf(w1, bf2f(r1[i]), a[i]);
#pragma unroll
      for (int i = 0; i < 8; ++i) a[i] = fmaf(w2, bf2f(r2[i]), a[i]);
#pragma unroll
      for (int i = 0; i < 8; ++i) a[i] = fmaf(w3, bf2f(r3[i]), a[i]);
    }
  }
#pragma unroll
  for (int i = 0; i < 8; ++i) a[i] += __shfl_xor(a[i], 16);
#pragma unroll
  for (int i = 0; i < 8; ++i) a[i] += __shfl_xor(a[i], 32);
  const u16x8 sv = *(const u16x8*)(Xf + (size_t)node * F);
#pragma unroll
  for (int i = 0; i < 8; ++i) a[i] = fmaf(di, bf2f(sv[i]), a[i]);
  if (sub == 0) {
    u16x8 o;
#pragma unroll
    for (int i = 0; i < 8; ++i) o[i] = f2bf(di * a[i]);
    *(u16x8*)(Y + (size_t)node * F + foff + fl * 8) = o;
  }
}

// ---------------- GEMM: out = relu(A[M,K](bf16) @ W[K,256](bf16) + b(fp32)), bf16 out ----------------
template <int K>  // 128 or 256
__global__ __launch_bounds__(512) void k_gemm(const unsigned short* __restrict__ A,
                                              const unsigned short* __restrict__ Wsw,
                                              const float* __restrict__ bias,
                                              unsigned short* __restrict__ out) {
  __shared__ unsigned short lW[128 * 256];  // 64 KB: one K-half of swizzled W
  const int tid = threadIdx.x;
  const int wave = tid >> 6;
  const int lane = tid & 63;
  const int q = lane >> 4;
  const int m16 = lane & 15;
  const size_t baseM = (size_t)blockIdx.x * 256;

  floatx4 acc[2][16];
#pragma unroll
  for (int t = 0; t < 2; ++t)
#pragma unroll
    for (int nt = 0; nt < 16; ++nt) acc[t][nt] = (floatx4){0.f, 0.f, 0.f, 0.f};

  const size_t rowA0 = baseM + wave * 32 + m16;
  const size_t rowA1 = rowA0 + 16;

  for (int half = 0; half < K / 128; ++half) {
    __syncthreads();
    const uint4* gsrc = (const uint4*)(Wsw + half * 32768);
    uint4* ldst = (uint4*)lW;
#pragma unroll
    for (int i = 0; i < 8; ++i) ldst[i * 512 + tid] = gsrc[i * 512 + tid];
    __syncthreads();

#pragma unroll
    for (int kc = 0; kc < 4; ++kc) {
      const int koff = half * 128 + kc * 32 + q * 8;
      const bf16x8 av0 = *(const bf16x8*)(A + rowA0 * K + koff);
      const bf16x8 av1 = *(const bf16x8*)(A + rowA1 * K + koff);
#pragma unroll
      for (int nt = 0; nt < 16; ++nt) {
        const bf16x8 bv = *(const bf16x8*)(&lW[(kc * 16 + nt) * 512 + lane * 8]);
        acc[0][nt] = __builtin_amdgcn_mfma_f32_16x16x32_bf16(av0, bv, acc[0][nt], 0, 0, 0);
        acc[1][nt] = __builtin_amdgcn_mfma_f32_16x16x32_bf16(av1, bv, acc[1][nt], 0, 0, 0);
      }
    }
  }
  const int rq = (lane >> 4) * 4;
#pragma unroll
  for (int t = 0; t < 2; ++t) {
#pragma unroll
    for (int nt = 0; nt < 16; ++nt) {
      const int col = nt * 16 + m16;
      const float bv = bias[col];
#pragma unroll
      for (int r = 0; r < 4; ++r) {
        const size_t row = baseM + wave * 32 + t * 16 + rq + r;
        float v = acc[t][nt][r] + bv;
        v = fmaxf(v, 0.0f);
        out[row * 256 + col] = f2bf(v);
      }
    }
  }
}

// ---------------- GEMM layer-2 + fused readout ----------------
__global__ __launch_bounds__(512) void k_gemm_out(const unsigned short* __restrict__ A,
                                                  const unsigned short* __restrict__ Wsw,
                                                  const float* __restrict__ bias,
                                                  const float* __restrict__ Wout,
                                                  const float* __restrict__ bout,
                                                  float* __restrict__ out) {
  constexpr int K = 256;
  __shared__ unsigned short lW[128 * 256];
  const int tid = threadIdx.x;
  const int wave = tid >> 6;
  const int lane = tid & 63;
  const int q = lane >> 4;
  const int m16 = lane & 15;
  const size_t baseM = (size_t)blockIdx.x * 256;

  floatx4 acc[2][16];
#pragma unroll
  for (int t = 0; t < 2; ++t)
#pragma unroll
    for (int nt = 0; nt < 16; ++nt) acc[t][nt] = (floatx4){0.f, 0.f, 0.f, 0.f};

  const size_t rowA0 = baseM + wave * 32 + m16;
  const size_t rowA1 = rowA0 + 16;

  for (int half = 0; half < 2; ++half) {
    __syncthreads();
    const uint4* gsrc = (const uint4*)(Wsw + half * 32768);
    uint4* ldst = (uint4*)lW;
#pragma unroll
    for (int i = 0; i < 8; ++i) ldst[i * 512 + tid] = gsrc[i * 512 + tid];
    __syncthreads();

#pragma unroll
    for (int kc = 0; kc < 4; ++kc) {
      const int koff = half * 128 + kc * 32 + q * 8;
      const bf16x8 av0 = *(const bf16x8*)(A + rowA0 * K + koff);
      const bf16x8 av1 = *(const bf16x8*)(A + rowA1 * K + koff);
#pragma unroll
      for (int nt = 0; nt < 16; ++nt) {
        const bf16x8 bv = *(const bf16x8*)(&lW[(kc * 16 + nt) * 512 + lane * 8]);
        acc[0][nt] = __builtin_amdgcn_mfma_f32_16x16x32_bf16(av0, bv, acc[0][nt], 0, 0, 0);
        acc[1][nt] = __builtin_amdgcn_mfma_f32_16x16x32_bf16(av1, bv, acc[1][nt], 0, 0, 0);
      }
    }
  }
  const int rq = (lane >> 4) * 4;
  float p0 = 0.f, p1 = 0.f;
#pragma unroll
  for (int nt = 0; nt < 16; ++nt) {
    const int col = nt * 16 + m16;
    const float bv = bias[col];
#pragma unroll
    for (int r = 0; r < 4; ++r) {
      const float wv = Wout[(rq + r) * 256 + col];  // k = (row%16)*256 + col
      const float v0 = fmaxf(acc[0][nt][r] + bv, 0.0f);
      const float v1 = fmaxf(acc[1][nt][r] + bv, 0.0f);
      p0 = fmaf(v0, wv, p0);
      p1 = fmaf(v1, wv, p1);
    }
  }
#pragma unroll
  for (int off = 32; off > 0; off >>= 1) {
    p0 += __shfl_xor(p0, off);
    p1 += __shfl_xor(p1, off);
  }
  if (lane == 0) {
    const float bo = bout[0];
    const int g = blockIdx.x * 16 + wave * 2;
    out[g]     = p0 + bo;
    out[g + 1] = p1 + bo;
  }
}

extern "C" void kernel_launch(void* const* d_in, const int* in_sizes, int n_in,
                              void* d_out, int out_size, void* d_ws, size_t ws_size,
                              hipStream_t stream) {
  const float* x    = (const float*)d_in[0];  // [N,128] fp32
  const int*   ei   = (const int*)d_in[1];    // [2,E] int32
  const float* W1   = (const float*)d_in[2];  // [128,256] fp32
  const float* b1   = (const float*)d_in[3];
  const float* W2   = (const float*)d_in[4];  // [256,256] fp32
  const float* b2   = (const float*)d_in[5];
  const float* Wout = (const float*)d_in[6];  // [4096] fp32
  const float* bout = (const float*)d_in[7];
  float* out = (float*)d_out;

  char* ws = (char*)d_ws;
  size_t off = 0;
  auto alloc = [&](size_t bytes) {
    char* p = ws + off;
    off += (bytes + 511) & ~(size_t)511;
    return p;
  };
  int*            row_ptr = (int*)alloc(((size_t)NN + 1) * 4);
  float*          dinv    = (float*)alloc((size_t)NN * 4);
  int*            bktCnt  = (int*)alloc(BKT * 4);
  unsigned int*   bktBuf  = (unsigned int*)alloc((size_t)BKT * BCAP * 4);  // 21 MB
  int*            csr     = (int*)alloc((size_t)NE * 4);
  unsigned short* Wsw1    = (unsigned short*)alloc(128 * 256 * 2);
  unsigned short* Wsw2    = (unsigned short*)alloc(256 * 256 * 2);
  unsigned short* xb      = (unsigned short*)alloc((size_t)NN * 128 * 2);
  unsigned short* bufA    = (unsigned short*)alloc((size_t)NN * 256 * 2);
  unsigned short* bufB    = (unsigned short*)alloc((size_t)NN * 256 * 2);
  (void)in_sizes; (void)n_in; (void)out_size; (void)ws_size;

  const int* src = ei;
  const int* dst = ei + NE;

  hipLaunchKernelGGL(k_bzero,  dim3(1), dim3(256), 0, stream, bktCnt);
  hipLaunchKernelGGL(k_bucket, dim3(NE / 4096), dim3(1024), 0, stream, src, dst, bktCnt, bktBuf);
  hipLaunchKernelGGL(k_csr,    dim3(BKT), dim3(1024), 0, stream, bktCnt, bktBuf, row_ptr, dinv, csr);
  hipLaunchKernelGGL(k_cvt,    dim3(NN * 128 / 4 / 256), dim3(256), 0, stream, x, xb);
  hipLaunchKernelGGL(k_swizzle2, dim3(384), dim3(256), 0, stream, W1, Wsw1, W2, Wsw2);

  // layer 1: full-row pass split in node-halves (visibility)
  hipLaunchKernelGGL(agg_h, dim3(NN / 8), dim3(256), 0, stream, xb, row_ptr, csr, dinv, bufA, 128, 0, 0);
  hipLaunchKernelGGL(agg_h, dim3(NN / 8), dim3(256), 0, stream, xb, row_ptr, csr, dinv, bufA, 128, 0, NN / 2);
  hipLaunchKernelGGL(k_gemm<128>, dim3(NN / 256), dim3(512), 0, stream, bufA, Wsw1, b1, bufB);
  // layer 2: two feature-half passes, each split in node-halves
  hipLaunchKernelGGL(agg_h, dim3(NN / 8), dim3(256), 0, stream, bufB, row_ptr, csr, dinv, bufA, 256, 0, 0);
  hipLaunchKernelGGL(agg_h, dim3(NN / 8), dim3(256), 0, stream, bufB, row_ptr, csr, dinv, bufA, 256, 0, NN / 2);
  hipLaunchKernelGGL(agg_h, dim3(NN / 8), dim3(256), 0, stream, bufB, row_ptr, csr, dinv, bufA, 256, 128, 0);
  hipLaunchKernelGGL(agg_h, dim3(NN / 8), dim3(256), 0, stream, bufB, row_ptr, csr, dinv, bufA, 256, 128, NN / 2);
  // layer-2 GEMM with fused readout (writes out directly)
  hipLaunchKernelGGL(k_gemm_out, dim3(NN / 256), dim3(512), 0, stream, bufA, Wsw2, b2, Wout, bout, out);
}

// Round 11
// 705.098 us; speedup vs baseline: 1.0380x; 1.0380x over previous
//
#include <hip/hip_runtime.h>
#include <stdint.h>

#define NN 131072
#define NE 4194304
#define BKT 256      // buckets (512 nodes each)
#define BKT_SH 9
#define BCAP 20480   // bucket capacity; mean 16384, sigma ~128

typedef __bf16 bf16x8 __attribute__((ext_vector_type(8)));
typedef float  floatx4 __attribute__((ext_vector_type(4)));
typedef unsigned short u16x8 __attribute__((ext_vector_type(8)));

__device__ __forceinline__ float bf2f(unsigned short u) {
  union { unsigned int i; float f; } v; v.i = ((unsigned int)u) << 16; return v.f;
}
__device__ __forceinline__ unsigned short f2bf(float f) {
  union { float f; unsigned int i; } v; v.f = f;
  unsigned int r = v.i + 0x7fffu + ((v.i >> 16) & 1u);  // RNE
  return (unsigned short)(r >> 16);
}

// ---------------- CSR build: LDS-histogram bucketing ----------------

__global__ __launch_bounds__(256) void k_bzero(int* __restrict__ bktCnt) {
  bktCnt[threadIdx.x] = 0;
}

// pass A v2: bin 4096 edges/block into LDS by dst-bucket, then write
// bucket-contiguous runs (avg 16 edges = 64B) -> kills the 16x write amp
// of direct 4B scatter. packed edge = (src<<9)|(dst&511).
__global__ __launch_bounds__(1024) void k_bucket(const int* __restrict__ src,
                                                 const int* __restrict__ dst,
                                                 int* __restrict__ bktCnt,
                                                 unsigned int* __restrict__ bktBuf) {
  __shared__ int hist[BKT];
  __shared__ int lofs[BKT];         // inclusive scan of hist
  __shared__ int gbase[BKT];        // global base - local exclusive offset
  __shared__ unsigned int ebuf[4096];
  __shared__ unsigned char bkt[4096];
  const int t = threadIdx.x;
  if (t < BKT) hist[t] = 0;
  __syncthreads();
  const int e0 = blockIdx.x * 1024 + t;
  const int4 s = ((const int4*)src)[e0];
  const int4 d = ((const int4*)dst)[e0];
  const int b0 = ((unsigned)d.x) >> BKT_SH, b1 = ((unsigned)d.y) >> BKT_SH;
  const int b2 = ((unsigned)d.z) >> BKT_SH, b3 = ((unsigned)d.w) >> BKT_SH;
  const int r0 = atomicAdd(&hist[b0], 1);
  const int r1 = atomicAdd(&hist[b1], 1);
  const int r2 = atomicAdd(&hist[b2], 1);
  const int r3 = atomicAdd(&hist[b3], 1);
  __syncthreads();
  if (t < BKT) lofs[t] = hist[t];
  __syncthreads();
  for (int off = 1; off < BKT; off <<= 1) {
    int v = 0;
    if (t < BKT && t >= off) v = lofs[t - off];
    __syncthreads();
    if (t < BKT) lofs[t] += v;
    __syncthreads();
  }
  // LDS scatter: slot = exclusive_ofs[b] + rank
  {
    const int s0i = lofs[b0] - hist[b0] + r0;
    const int s1i = lofs[b1] - hist[b1] + r1;
    const int s2i = lofs[b2] - hist[b2] + r2;
    const int s3i = lofs[b3] - hist[b3] + r3;
    ebuf[s0i] = (((unsigned)s.x) << BKT_SH) | (d.x & 511); bkt[s0i] = (unsigned char)b0;
    ebuf[s1i] = (((unsigned)s.y) << BKT_SH) | (d.y & 511); bkt[s1i] = (unsigned char)b1;
    ebuf[s2i] = (((unsigned)s.z) << BKT_SH) | (d.z & 511); bkt[s2i] = (unsigned char)b2;
    ebuf[s3i] = (((unsigned)s.w) << BKT_SH) | (d.w & 511); bkt[s3i] = (unsigned char)b3;
  }
  // reserve global runs; gbase folds in -local_exclusive so copy uses +i
  if (t < BKT)
    gbase[t] = atomicAdd(&bktCnt[t], hist[t]) - (lofs[t] - hist[t]);
  __syncthreads();
  // coalesced-run copy out
  for (int i = t; i < 4096; i += 1024) {
    const int bb = bkt[i];
    bktBuf[(size_t)bb * BCAP + gbase[bb] + i] = ebuf[i];
  }
}

// pass B: one block per bucket -> counts, row_ptr, dinv, csr fill
// 2-replica LDS histograms halve atomic contention.
__global__ __launch_bounds__(1024) void k_csr(const int* __restrict__ bktCnt,
                                              const unsigned int* __restrict__ bktBuf,
                                              int* __restrict__ row_ptr,
                                              float* __restrict__ dinv,
                                              int* __restrict__ csr) {
  __shared__ int bsum[BKT];
  __shared__ int histA[512];
  __shared__ int histB[512];
  __shared__ int sc[512];
  __shared__ int curA[512];
  __shared__ int curB[512];
  const int b = blockIdx.x;
  const int t = threadIdx.x;
  const int rep = t & 1;
  if (t < BKT) bsum[t] = bktCnt[t];
  if (t < 512) { histA[t] = 0; histB[t] = 0; }
  __syncthreads();
  // inclusive scan of bucket sizes (256)
  for (int off = 1; off < BKT; off <<= 1) {
    int v = 0;
    if (t < BKT && t >= off) v = bsum[t - off];
    __syncthreads();
    if (t < BKT) bsum[t] += v;
    __syncthreads();
  }
  const int sz = bktCnt[b];
  const int csrBase = bsum[b] - sz;  // exclusive prefix
  const unsigned int* eb = bktBuf + (size_t)b * BCAP;
  // local node histogram, replica by thread parity
  for (int i = t; i < sz; i += 1024)
    atomicAdd(rep ? &histB[eb[i] & 511] : &histA[eb[i] & 511], 1);
  __syncthreads();
  if (t < 512) sc[t] = histA[t] + histB[t];
  __syncthreads();
  for (int off = 1; off < 512; off <<= 1) {
    int v = 0;
    if (t < 512 && t >= off) v = sc[t - off];
    __syncthreads();
    if (t < 512) sc[t] += v;
    __syncthreads();
  }
  if (t < 512) {
    const int cnt = histA[t] + histB[t];
    const int ex = csrBase + sc[t] - cnt;  // exclusive
    row_ptr[b * 512 + t] = ex;
    curA[t] = ex;                 // replica-A fills [ex, ex+histA)
    curB[t] = ex + histA[t];      // replica-B fills [ex+histA, ex+cnt)
    dinv[b * 512 + t] = rsqrtf((float)(cnt + 1));
  }
  if (b == BKT - 1 && t == 0) row_ptr[NN] = NE;
  __syncthreads();
  // fill csr (bucket csr region = 64 KB -> L2-resident writes)
  for (int i = t; i < sz; i += 1024) {
    const unsigned e = eb[i];
    const int n = e & 511;
    const int pos = atomicAdd(rep ? &curB[n] : &curA[n], 1);
    csr[pos] = (int)(e >> BKT_SH);
  }
}

// ---------------- x fp32 -> bf16 ----------------
__global__ __launch_bounds__(256) void k_cvt(const float* __restrict__ X,
                                             unsigned short* __restrict__ Xb) {
  const int t = blockIdx.x * 256 + threadIdx.x;
  const float4 v = ((const float4*)X)[t];
  ushort4 o;
  o.x = f2bf(v.x); o.y = f2bf(v.y); o.z = f2bf(v.z); o.w = f2bf(v.w);
  ((ushort4*)Xb)[t] = o;
}

// ---------------- W1+W2 swizzle in one launch (fp32 -> bf16, MFMA B-frag order) ----------------
__global__ __launch_bounds__(256) void k_swizzle2(const float* __restrict__ W1,
                                                  unsigned short* __restrict__ Wsw1,
                                                  const float* __restrict__ W2,
                                                  unsigned short* __restrict__ Wsw2) {
  int b = blockIdx.x;
  const float* W; unsigned short* Wsw;
  if (b < 128) { W = W1; Wsw = Wsw1; } else { W = W2; Wsw = Wsw2; b -= 128; }
  const int t = b * 256 + threadIdx.x;  // t < K*256
  const int k = t >> 8, n = t & 255;
  const int s = ((k >> 5) * 16 + (n >> 4)) * 512 + ((k >> 3) & 3) * 128 + (n & 15) * 8 + (k & 7);
  Wsw[s] = f2bf(W[t]);
}

// ---------------- aggregation, feature-sliced pass ----------------
// One wave per node. 16 lanes per row gather 128 contiguous feats at foff.
__global__ __launch_bounds__(256) void agg_h(const unsigned short* __restrict__ X,
                                             const int* __restrict__ row_ptr,
                                             const int* __restrict__ csr,
                                             const float* __restrict__ dinv,
                                             unsigned short* __restrict__ Y,
                                             int F, int foff) {
  const int lane = threadIdx.x & 63;
  const int node = (blockIdx.x * blockDim.x + threadIdx.x) >> 6;
  const int sub = lane >> 4;   // 0..3
  const int fl = lane & 15;
  const int start = row_ptr[node];
  const int end = row_ptr[node + 1];
  const float di = dinv[node];
  float a[8] = {0.f, 0.f, 0.f, 0.f, 0.f, 0.f, 0.f, 0.f};
  const unsigned short* Xf = X + foff + fl * 8;

  for (int e = start; e < end; e += 64) {
    const int nload = min(end - e, 64);
    int s_l = node;
    float w_l = 0.0f;
    if (lane < nload) {
      s_l = __builtin_nontemporal_load(&csr[e + lane]);
      w_l = dinv[s_l];
    }
    for (int j = 0; j < nload; j += 16) {
      const int i0 = j + sub, i1 = j + 4 + sub, i2 = j + 8 + sub, i3 = j + 12 + sub;  // <= 63
      const int s0 = __shfl(s_l, i0); const float w0 = __shfl(w_l, i0);
      const int s1 = __shfl(s_l, i1); const float w1 = __shfl(w_l, i1);
      const int s2 = __shfl(s_l, i2); const float w2 = __shfl(w_l, i2);
      const int s3 = __shfl(s_l, i3); const float w3 = __shfl(w_l, i3);
      const u16x8 r0 = *(const u16x8*)(Xf + (size_t)s0 * F);
      const u16x8 r1 = *(const u16x8*)(Xf + (size_t)s1 * F);
      const u16x8 r2 = *(const u16x8*)(Xf + (size_t)s2 * F);
      const u16x8 r3 = *(const u16x8*)(Xf + (size_t)s3 * F);
#pragma unroll
      for (int i = 0; i < 8; ++i) a[i] = fmaf(w0, bf2f(r0[i]), a[i]);
#pragma unroll
      for (int i = 0; i < 8; ++i) a[i] = fmaf(w1, bf2f(r1[i]), a[i]);
#pragma unroll
      for (int i = 0; i < 8; ++i) a[i] = fmaf(w2, bf2f(r2[i]), a[i]);
#pragma unroll
      for (int i = 0; i < 8; ++i) a[i] = fmaf(w3, bf2f(r3[i]), a[i]);
    }
  }
#pragma unroll
  for (int i = 0; i < 8; ++i) a[i] += __shfl_xor(a[i], 16);
#pragma unroll
  for (int i = 0; i < 8; ++i) a[i] += __shfl_xor(a[i], 32);
  const u16x8 sv = *(const u16x8*)(Xf + (size_t)node * F);
#pragma unroll
  for (int i = 0; i < 8; ++i) a[i] = fmaf(di, bf2f(sv[i]), a[i]);
  if (sub == 0) {
    u16x8 o;
#pragma unroll
    for (int i = 0; i < 8; ++i) o[i] = f2bf(di * a[i]);
    *(u16x8*)(Y + (size_t)node * F + foff + fl * 8) = o;
  }
}

// ---------------- GEMM: out = relu(A[M,K](bf16) @ W[K,256](bf16) + b(fp32)), bf16 out ----------------
template <int K>  // 128 or 256
__global__ __launch_bounds__(512) void k_gemm(const unsigned short* __restrict__ A,
                                              const unsigned short* __restrict__ Wsw,
                                              const float* __restrict__ bias,
                                              unsigned short* __restrict__ out) {
  __shared__ unsigned short lW[128 * 256];  // 64 KB: one K-half of swizzled W
  const int tid = threadIdx.x;
  const int wave = tid >> 6;
  const int lane = tid & 63;
  const int q = lane >> 4;
  const int m16 = lane & 15;
  const size_t baseM = (size_t)blockIdx.x * 256;

  floatx4 acc[2][16];
#pragma unroll
  for (int t = 0; t < 2; ++t)
#pragma unroll
    for (int nt = 0; nt < 16; ++nt) acc[t][nt] = (floatx4){0.f, 0.f, 0.f, 0.f};

  const size_t rowA0 = baseM + wave * 32 + m16;
  const size_t rowA1 = rowA0 + 16;

  for (int half = 0; half < K / 128; ++half) {
    __syncthreads();
    const uint4* gsrc = (const uint4*)(Wsw + half * 32768);
    uint4* ldst = (uint4*)lW;
#pragma unroll
    for (int i = 0; i < 8; ++i) ldst[i * 512 + tid] = gsrc[i * 512 + tid];
    __syncthreads();

#pragma unroll
    for (int kc = 0; kc < 4; ++kc) {
      const int koff = half * 128 + kc * 32 + q * 8;
      const bf16x8 av0 = *(const bf16x8*)(A + rowA0 * K + koff);
      const bf16x8 av1 = *(const bf16x8*)(A + rowA1 * K + koff);
#pragma unroll
      for (int nt = 0; nt < 16; ++nt) {
        const bf16x8 bv = *(const bf16x8*)(&lW[(kc * 16 + nt) * 512 + lane * 8]);
        acc[0][nt] = __builtin_amdgcn_mfma_f32_16x16x32_bf16(av0, bv, acc[0][nt], 0, 0, 0);
        acc[1][nt] = __builtin_amdgcn_mfma_f32_16x16x32_bf16(av1, bv, acc[1][nt], 0, 0, 0);
      }
    }
  }
  const int rq = (lane >> 4) * 4;
#pragma unroll
  for (int t = 0; t < 2; ++t) {
#pragma unroll
    for (int nt = 0; nt < 16; ++nt) {
      const int col = nt * 16 + m16;
      const float bv = bias[col];
#pragma unroll
      for (int r = 0; r < 4; ++r) {
        const size_t row = baseM + wave * 32 + t * 16 + rq + r;
        float v = acc[t][nt][r] + bv;
        v = fmaxf(v, 0.0f);
        out[row * 256 + col] = f2bf(v);
      }
    }
  }
}

// ---------------- GEMM layer-2 + fused readout ----------------
__global__ __launch_bounds__(512) void k_gemm_out(const unsigned short* __restrict__ A,
                                                  const unsigned short* __restrict__ Wsw,
                                                  const float* __restrict__ bias,
                                                  const float* __restrict__ Wout,
                                                  const float* __restrict__ bout,
                                                  float* __restrict__ out) {
  constexpr int K = 256;
  __shared__ unsigned short lW[128 * 256];
  const int tid = threadIdx.x;
  const int wave = tid >> 6;
  const int lane = tid & 63;
  const int q = lane >> 4;
  const int m16 = lane & 15;
  const size_t baseM = (size_t)blockIdx.x * 256;

  floatx4 acc[2][16];
#pragma unroll
  for (int t = 0; t < 2; ++t)
#pragma unroll
    for (int nt = 0; nt < 16; ++nt) acc[t][nt] = (floatx4){0.f, 0.f, 0.f, 0.f};

  const size_t rowA0 = baseM + wave * 32 + m16;
  const size_t rowA1 = rowA0 + 16;

  for (int half = 0; half < 2; ++half) {
    __syncthreads();
    const uint4* gsrc = (const uint4*)(Wsw + half * 32768);
    uint4* ldst = (uint4*)lW;
#pragma unroll
    for (int i = 0; i < 8; ++i) ldst[i * 512 + tid] = gsrc[i * 512 + tid];
    __syncthreads();

#pragma unroll
    for (int kc = 0; kc < 4; ++kc) {
      const int koff = half * 128 + kc * 32 + q * 8;
      const bf16x8 av0 = *(const bf16x8*)(A + rowA0 * K + koff);
      const bf16x8 av1 = *(const bf16x8*)(A + rowA1 * K + koff);
#pragma unroll
      for (int nt = 0; nt < 16; ++nt) {
        const bf16x8 bv = *(const bf16x8*)(&lW[(kc * 16 + nt) * 512 + lane * 8]);
        acc[0][nt] = __builtin_amdgcn_mfma_f32_16x16x32_bf16(av0, bv, acc[0][nt], 0, 0, 0);
        acc[1][nt] = __builtin_amdgcn_mfma_f32_16x16x32_bf16(av1, bv, acc[1][nt], 0, 0, 0);
      }
    }
  }
  const int rq = (lane >> 4) * 4;
  float p0 = 0.f, p1 = 0.f;
#pragma unroll
  for (int nt = 0; nt < 16; ++nt) {
    const int col = nt * 16 + m16;
    const float bv = bias[col];
#pragma unroll
    for (int r = 0; r < 4; ++r) {
      const float wv = Wout[(rq + r) * 256 + col];  // k = (row%16)*256 + col
      const float v0 = fmaxf(acc[0][nt][r] + bv, 0.0f);
      const float v1 = fmaxf(acc[1][nt][r] + bv, 0.0f);
      p0 = fmaf(v0, wv, p0);
      p1 = fmaf(v1, wv, p1);
    }
  }
#pragma unroll
  for (int off = 32; off > 0; off >>= 1) {
    p0 += __shfl_xor(p0, off);
    p1 += __shfl_xor(p1, off);
  }
  if (lane == 0) {
    const float bo = bout[0];
    const int g = blockIdx.x * 16 + wave * 2;
    out[g]     = p0 + bo;
    out[g + 1] = p1 + bo;
  }
}

extern "C" void kernel_launch(void* const* d_in, const int* in_sizes, int n_in,
                              void* d_out, int out_size, void* d_ws, size_t ws_size,
                              hipStream_t stream) {
  const float* x    = (const float*)d_in[0];  // [N,128] fp32
  const int*   ei   = (const int*)d_in[1];    // [2,E] int32
  const float* W1   = (const float*)d_in[2];  // [128,256] fp32
  const float* b1   = (const float*)d_in[3];
  const float* W2   = (const float*)d_in[4];  // [256,256] fp32
  const float* b2   = (const float*)d_in[5];
  const float* Wout = (const float*)d_in[6];  // [4096] fp32
  const float* bout = (const float*)d_in[7];
  float* out = (float*)d_out;

  char* ws = (char*)d_ws;
  size_t off = 0;
  auto alloc = [&](size_t bytes) {
    char* p = ws + off;
    off += (bytes + 511) & ~(size_t)511;
    return p;
  };
  int*            row_ptr = (int*)alloc(((size_t)NN + 1) * 4);
  float*          dinv    = (float*)alloc((size_t)NN * 4);
  int*            bktCnt  = (int*)alloc(BKT * 4);
  unsigned int*   bktBuf  = (unsigned int*)alloc((size_t)BKT * BCAP * 4);  // 21 MB
  int*            csr     = (int*)alloc((size_t)NE * 4);
  unsigned short* Wsw1    = (unsigned short*)alloc(128 * 256 * 2);
  unsigned short* Wsw2    = (unsigned short*)alloc(256 * 256 * 2);
  unsigned short* xb      = (unsigned short*)alloc((size_t)NN * 128 * 2);
  unsigned short* bufA    = (unsigned short*)alloc((size_t)NN * 256 * 2);
  unsigned short* bufB    = (unsigned short*)alloc((size_t)NN * 256 * 2);
  (void)in_sizes; (void)n_in; (void)out_size; (void)ws_size;

  const int* src = ei;
  const int* dst = ei + NE;

  hipLaunchKernelGGL(k_bzero,  dim3(1), dim3(256), 0, stream, bktCnt);
  hipLaunchKernelGGL(k_bucket, dim3(NE / 4096), dim3(1024), 0, stream, src, dst, bktCnt, bktBuf);
  hipLaunchKernelGGL(k_csr,    dim3(BKT), dim3(1024), 0, stream, bktCnt, bktBuf, row_ptr, dinv, csr);
  hipLaunchKernelGGL(k_cvt,    dim3(NN * 128 / 4 / 256), dim3(256), 0, stream, x, xb);
  hipLaunchKernelGGL(k_swizzle2, dim3(384), dim3(256), 0, stream, W1, Wsw1, W2, Wsw2);

  // layer 1: single full-row pass (Agg(X)@W1 == Agg(X@W1))
  hipLaunchKernelGGL(agg_h, dim3(NN / 4), dim3(256), 0, stream, xb, row_ptr, csr, dinv, bufA, 128, 0);
  hipLaunchKernelGGL(k_gemm<128>, dim3(NN / 256), dim3(512), 0, stream, bufA, Wsw1, b1, bufB);
  // layer 2: two feature-half passes
  hipLaunchKernelGGL(agg_h, dim3(NN / 4), dim3(256), 0, stream, bufB, row_ptr, csr, dinv, bufA, 256, 0);
  hipLaunchKernelGGL(agg_h, dim3(NN / 4), dim3(256), 0, stream, bufB, row_ptr, csr, dinv, bufA, 256, 128);
  // layer-2 GEMM with fused readout (writes out directly)
  hipLaunchKernelGGL(k_gemm_out, dim3(NN / 256), dim3(512), 0, stream, bufA, Wsw2, b2, Wout, bout, out);
}